// Round 18
// baseline (40.399 us; speedup 1.0000x reference)
//
#include <hip/hip_runtime.h>

#define DD 1024
#define HALO 32
#define IMGF (2 * (HALO + DD + HALO))   // floats per interleaved row image = 2176 = 17*128
// K=2 minimax-Cayley (validated r17, absmax 0.03125 == noise floor):
//   y1 = rot + C1*(H rot)^perp ; x = rot + C2*(H y1)^perp
//   C1 = (c2/c1)*h = 0.0498693, C2 = -c1*h = 0.0975700  (h = dt/2)
// This round: SINGLE buffer per row (rot image is dead after step-1 reads)
// -> LDS 34.8 KB -> 17.4 KB per block -> residency cap 4 -> 8 blocks/CU.
// Cost: one extra barrier (store -> B1 -> read -> B2 -> store -> B3 -> read).
#define C1_F 0.0498693f
#define C2_F 0.0975700f

typedef float f2 __attribute__((ext_vector_type(2)));   // (re, im) -> VGPR pair

// d -= w * v, w = uniform SGPR pair {w,w} (forced VOP3P packed FMA)
__device__ __forceinline__ void pk_fnma_s(f2& d, unsigned long long w, f2 v) {
    asm("v_pk_fma_f32 %0, %1, %2, %0 neg_lo:[1,0,0] neg_hi:[1,0,0]"
        : "+v"(d) : "s"(w), "v"(v));
}

// XOR swizzle on float index. Involution; preserves 16B alignment; commutes
// with multiples of 128 floats: IMGF row stride, +-2*DD halo shifts.
__device__ __forceinline__ int swzf(int f) { return f ^ (((f >> 5) & 3) << 2); }

// Wave64 sum via DPP (prologue only). Total valid in lane 63 ONLY.
__device__ __forceinline__ float dpp_wave_sum(float v) {
    int b;
    b = __builtin_amdgcn_update_dpp(0, __float_as_int(v), 0x111, 0xf, 0xf, true); v += __int_as_float(b);
    b = __builtin_amdgcn_update_dpp(0, __float_as_int(v), 0x112, 0xf, 0xf, true); v += __int_as_float(b);
    b = __builtin_amdgcn_update_dpp(0, __float_as_int(v), 0x114, 0xf, 0xf, true); v += __int_as_float(b);
    b = __builtin_amdgcn_update_dpp(0, __float_as_int(v), 0x118, 0xf, 0xf, true); v += __int_as_float(b);
    b = __builtin_amdgcn_update_dpp(0, __float_as_int(v), 0x142, 0xa, 0xf, true); v += __int_as_float(b);
    b = __builtin_amdgcn_update_dpp(0, __float_as_int(v), 0x143, 0xc, 0xf, true); v += __int_as_float(b);
    return v;
}

// Row-wide (128-thread, 2-wave) sum; exactly one barrier.
__device__ __forceinline__ float row_sum(float v, float* red, int wave, int rw) {
    v = dpp_wave_sum(v);
    if ((threadIdx.x & 63) == 63) red[wave] = v;
    __syncthreads();
    return red[2 * rw] + red[2 * rw + 1];
}

// Packed H-apply on this thread's 8 complex elements (center in regs).
__device__ __forceinline__ void hmat8p(const float* lds, const int raL[10], const int raR[10],
                                       const unsigned long long wp[11],
                                       const float diag[8], const f2 pc[8], f2 H[8]) {
    constexpr int taps[11] = {1, 2, 3, 4, 5, 6, 8, 10, 12, 16, 20};
    {   // pass L: left 20 complex + all center-resident taps
        f2 lw[20];
#pragma unroll
        for (int k = 0; k < 10; ++k) {
            float4 v = *reinterpret_cast<const float4*>(&lds[raL[k]]);
            lw[2 * k] = f2{v.x, v.y};
            lw[2 * k + 1] = f2{v.z, v.w};
        }
#pragma unroll
        for (int i = 0; i < 8; ++i) {
            f2 acc = f2{diag[i] * pc[i].x, diag[i] * pc[i].y};
#pragma unroll
            for (int j = 0; j < 11; ++j) {
                const int n = i - taps[j];
                pk_fnma_s(acc, wp[j], (n >= 0) ? pc[n] : lw[20 + n]);
                const int m = i + taps[j];
                if (m <= 7) pk_fnma_s(acc, wp[j], pc[m]);
            }
            H[i] = acc;
        }
    }
    {   // pass R: right 20 complex
        f2 rw2[20];
#pragma unroll
        for (int k = 0; k < 10; ++k) {
            float4 v = *reinterpret_cast<const float4*>(&lds[raR[k]]);
            rw2[2 * k] = f2{v.x, v.y};
            rw2[2 * k + 1] = f2{v.z, v.w};
        }
#pragma unroll
        for (int i = 0; i < 8; ++i) {
#pragma unroll
            for (int j = 0; j < 11; ++j) {
                const int m = i + taps[j];
                if (m > 7) pk_fnma_s(H[i], wp[j], rw2[m - 8]);
            }
        }
    }
}

// Store this thread's 8 interleaved complex (4 float4) + halo copies.
__device__ __forceinline__ void store_row8p(float* lds, const int wa[4], const int ha[4],
                                            bool hh, const f2 v[8]) {
#pragma unroll
    for (int j = 0; j < 4; ++j) {
        float4 a = make_float4(v[2 * j].x, v[2 * j].y, v[2 * j + 1].x, v[2 * j + 1].y);
        *reinterpret_cast<float4*>(&lds[wa[j]]) = a;
        if (hh) *reinterpret_cast<float4*>(&lds[ha[j]]) = a;
    }
}

__global__ void __launch_bounds__(256, 2)
cayley_kernel(const float* __restrict__ psi_r, const float* __restrict__ psi_i,
              const float* __restrict__ alpha, const float* __restrict__ sw,
              const float* __restrict__ potential, float* __restrict__ out) {
    // 2 rows x ONE image each, interleaved complex (single-buffered).
    __shared__ __align__(16) float lds[2 * IMGF];
    __shared__ float red0[4];

    const int t = threadIdx.x;
    const int u = t & 127;         // row-local thread: owns complex [8u, 8u+8)
    const int rw = t >> 7;         // row within block (0/1)
    const int wave = t >> 6;
    const int rb = rw * IMGF;      // row base: one buffer per row
    const int row = (blockIdx.x << 1) + rw;

    const float w0 = sw[0], w1 = sw[1], w2 = sw[2];
    const float cwv[11] = {w0, w0 + w1, w0, w0 + w1 + w2, w0, w1, w1 + w2, w1, w2, w2, w2};
    const float dadd = 10.0f * (w0 + w1 + w2);

    unsigned long long wp[11];
#pragma unroll
    for (int j = 0; j < 11; ++j) {
        const unsigned int b = __builtin_amdgcn_readfirstlane(__float_as_uint(cwv[j]));
        wp[j] = ((unsigned long long)b << 32) | b;
    }

    // Loop-invariant swizzled LDS float-index addresses.
    const int fb = rb + 2 * (HALO + 8 * u);
    int wa[4], raL[10], raR[10];
#pragma unroll
    for (int j = 0; j < 4; ++j) wa[j] = swzf(fb + 4 * j);
#pragma unroll
    for (int k = 0; k < 10; ++k) {
        raL[k] = swzf(fb - 40 + 4 * k);       // left 20 complex
        raR[k] = swzf(fb + 16 + 4 * k);       // right 20 complex
    }
    const bool hh = (u < 4) || (u >= 124);
    int ha[4] = {0, 0, 0, 0};
    if (u < 4) {
#pragma unroll
        for (int j = 0; j < 4; ++j) ha[j] = swzf(fb + 2 * DD + 4 * j);
    } else if (u >= 124) {
#pragma unroll
        for (int j = 0; j < 4; ++j) ha[j] = swzf(fb - 2 * DD + 4 * j);
    }

    // --- global loads: 8 complex per thread (planar in, packed regs) ---
    const size_t goff = (size_t)row * DD + 8 * u;
    f2 cur[8];                     // psi -> rot (kept through the whole kernel)
    float diag[8];
#pragma unroll
    for (int j = 0; j < 2; ++j) {
        float4 a = *reinterpret_cast<const float4*>(psi_r + goff + 4 * j);
        float4 b = *reinterpret_cast<const float4*>(psi_i + goff + 4 * j);
        float4 d = *reinterpret_cast<const float4*>(potential + 8 * u + 4 * j);
        cur[4 * j + 0] = f2{a.x, b.x};
        cur[4 * j + 1] = f2{a.y, b.y};
        cur[4 * j + 2] = f2{a.z, b.z};
        cur[4 * j + 3] = f2{a.w, b.w};
        diag[4 * j] = d.x + dadd; diag[4 * j + 1] = d.y + dadd;
        diag[4 * j + 2] = d.z + dadd; diag[4 * j + 3] = d.w + dadd;
    }

    // --- intensity mean over the row (the only reduction in the kernel) ---
    float isum = 0.f;
#pragma unroll
    for (int i = 0; i < 8; ++i) isum += cur[i].x * cur[i].x + cur[i].y * cur[i].y;
    const float tot = row_sum(isum, red0, wave, rw);
    const float inv_mean = 1.0f / (tot * (1.0f / DD) + 1e-8f);

    // --- nonlinear phase rotation (in place; cur := rot) ---
#pragma unroll
    for (int j = 0; j < 2; ++j) {
        float4 c = *reinterpret_cast<const float4*>(alpha + 8 * u + 4 * j);
        float av[4] = {c.x, c.y, c.z, c.w};
#pragma unroll
        for (int q = 0; q < 4; ++q) {
            const int i = 4 * j + q;
            const float ph = av[q] * ((cur[i].x * cur[i].x + cur[i].y * cur[i].y) * inv_mean);
            float s, cc;
            __sincosf(ph, &s, &cc);
            cur[i] = f2{cur[i].x * cc - cur[i].y * s, cur[i].x * s + cur[i].y * cc};
        }
    }

    // --- minimax-Cayley, 2 matvecs, single buffer, 3 barriers ---
    f2 y[8], Hy[8];

    // step 1: publish rot -> read H(rot)
    store_row8p(lds, wa, ha, hh, cur);
    __syncthreads();                       // B1: rot visible
    hmat8p(lds, raL, raR, wp, diag, cur, Hy);
#pragma unroll
    for (int i = 0; i < 8; ++i)
        y[i] = f2{cur[i].x + C1_F * Hy[i].y, cur[i].y - C1_F * Hy[i].x};

    // step 2: overwrite buffer with y1 (WAR fenced by B2) -> read H(y1)
    __syncthreads();                       // B2: all rot-window reads done
    store_row8p(lds, wa, ha, hh, y);
    __syncthreads();                       // B3: y1 visible
    hmat8p(lds, raL, raR, wp, diag, y, Hy);
#pragma unroll
    for (int i = 0; i < 8; ++i)
        y[i] = f2{cur[i].x + C2_F * Hy[i].y, cur[i].y - C2_F * Hy[i].x};

    // --- write x (= y); output [.., D, 2] == packed layout ---
    float* op = out + 2 * goff;
#pragma unroll
    for (int j = 0; j < 4; ++j) {
        *reinterpret_cast<float4*>(op + 4 * j) =
            make_float4(y[2 * j].x, y[2 * j].y, y[2 * j + 1].x, y[2 * j + 1].y);
    }
}

extern "C" void kernel_launch(void* const* d_in, const int* in_sizes, int n_in,
                              void* d_out, int out_size, void* d_ws, size_t ws_size,
                              hipStream_t stream) {
    const float* psi_r = (const float*)d_in[0];
    const float* psi_i = (const float*)d_in[1];
    const float* alpha = (const float*)d_in[2];
    const float* sw = (const float*)d_in[3];
    const float* pot = (const float*)d_in[4];
    float* out = (float*)d_out;
    const int rows = in_sizes[0] / DD;   // B*S = 8192
    cayley_kernel<<<dim3(rows / 2), dim3(256), 0, stream>>>(psi_r, psi_i, alpha, sw, pot, out);
}